// Round 2
// baseline (120.539 us; speedup 1.0000x reference)
//
#include <hip/hip_runtime.h>

// GATv1-style single-head attention, N=8192, F_in=128, F_out=64, alpha=0.2.
// exp(leakyrelu(s_i + d_j)) is separable per branch; the branch predicate is
// monotone in d_j. Sort by d, build block-sampled prefix sums (every 32 sorted
// elements) of e^d*Wh and e^{0.2d}*Wh plus scalar denominators; each output row
// is: binary search threshold + block-table lookup + <=31 residual terms.
// O(N^2 F) -> O(N(logN + F)).  Total ws footprint: ~2.28 MB (round-0's 6.5 MB
// overflowed ws and corrupted the harness's pristine input copies).

typedef unsigned long long ull;

constexpr int N_ROWS = 8192;
constexpr int F_IN   = 128;
constexpr int F_OUT  = 64;
#define LRELU_ALPHA 0.2f

constexpr int SBLK = 32;            // prefix-table sampling block
constexpr int NB   = N_ROWS / SBLK; // 256 boundaries; tables hold NB+1 entries

// workspace layout in floats (total 598,658 floats = 2.28 MB)
constexpr int WS_WH   = 0;                          // 8192*64 = 524288
constexpr int WS_ESRC = WS_WH + N_ROWS * F_OUT;     // 8192
constexpr int WS_KEYA = WS_ESRC + N_ROWS;           // 8192 ull = 16384 floats
constexpr int WS_KEYB = WS_KEYA + 2 * N_ROWS;       // 16384 floats
constexpr int WS_BP1  = WS_KEYB + 2 * N_ROWS;       // (NB+1)*64, layout [b][c]
constexpr int WS_BP2  = WS_BP1 + (NB + 1) * F_OUT;
constexpr int WS_BD1  = WS_BP2 + (NB + 1) * F_OUT;  // NB+1
constexpr int WS_BD2  = WS_BD1 + (NB + 1);
static_assert((WS_KEYA % 2) == 0 && (WS_KEYB % 2) == 0, "keys 8B-aligned");

// monotone float<->uint mapping (ascending uint order == ascending float order)
__device__ __forceinline__ unsigned mono_enc(float f) {
  unsigned u = __float_as_uint(f);
  return u ^ ((u & 0x80000000u) ? 0xFFFFFFFFu : 0x80000000u);
}
__device__ __forceinline__ float mono_dec(unsigned e) {
  unsigned u = e ^ ((e & 0x80000000u) ? 0x80000000u : 0xFFFFFFFFu);
  return __uint_as_float(u);
}

// ---------------- K1: Wh = h @ W ; e_src = Wh@a1 ; keys = (enc(Wh@a2), j) ----------------
// grid 512 x 256 threads. 16 rows/block, wave handles 4 rows, lane = output col.
__global__ __launch_bounds__(256) void k1_wh(const float* __restrict__ h,
                                             const float* __restrict__ W,
                                             const float* __restrict__ a,
                                             float* __restrict__ ws) {
  __shared__ float hlds[16 * F_IN];    // 8 KB
  __shared__ float alds[2 * F_OUT];
  const int t = threadIdx.x;
  const int row0 = blockIdx.x * 16;

  const float4* hsrc = (const float4*)(h + (long)row0 * F_IN);
  float4* hd = (float4*)hlds;
  hd[t]       = hsrc[t];
  hd[t + 256] = hsrc[t + 256];
  if (t < 2 * F_OUT) alds[t] = a[t];
  __syncthreads();

  const int wave = t >> 6, lane = t & 63;
  const float* hp = hlds + (wave * 4) * F_IN;
  float acc0 = 0.f, acc1 = 0.f, acc2 = 0.f, acc3 = 0.f;

  #pragma unroll 4
  for (int k4 = 0; k4 < F_IN; k4 += 4) {
    float4 h0 = *(const float4*)(hp + k4);
    float4 h1 = *(const float4*)(hp + F_IN + k4);
    float4 h2 = *(const float4*)(hp + 2 * F_IN + k4);
    float4 h3 = *(const float4*)(hp + 3 * F_IN + k4);
    float w0 = W[(k4 + 0) * F_OUT + lane];
    float w1 = W[(k4 + 1) * F_OUT + lane];
    float w2 = W[(k4 + 2) * F_OUT + lane];
    float w3 = W[(k4 + 3) * F_OUT + lane];
    acc0 = fmaf(h0.x, w0, acc0); acc0 = fmaf(h0.y, w1, acc0);
    acc0 = fmaf(h0.z, w2, acc0); acc0 = fmaf(h0.w, w3, acc0);
    acc1 = fmaf(h1.x, w0, acc1); acc1 = fmaf(h1.y, w1, acc1);
    acc1 = fmaf(h1.z, w2, acc1); acc1 = fmaf(h1.w, w3, acc1);
    acc2 = fmaf(h2.x, w0, acc2); acc2 = fmaf(h2.y, w1, acc2);
    acc2 = fmaf(h2.z, w2, acc2); acc2 = fmaf(h2.w, w3, acc2);
    acc3 = fmaf(h3.x, w0, acc3); acc3 = fmaf(h3.y, w1, acc3);
    acc3 = fmaf(h3.z, w2, acc3); acc3 = fmaf(h3.w, w3, acc3);
  }

  const int grow = row0 + wave * 4;
  float* Wh = ws + WS_WH;
  Wh[(grow + 0) * F_OUT + lane] = acc0;
  Wh[(grow + 1) * F_OUT + lane] = acc1;
  Wh[(grow + 2) * F_OUT + lane] = acc2;
  Wh[(grow + 3) * F_OUT + lane] = acc3;

  const float a1 = alds[lane], a2 = alds[F_OUT + lane];
  float s0 = acc0 * a1, s1 = acc1 * a1, s2 = acc2 * a1, s3 = acc3 * a1;
  float d0 = acc0 * a2, d1 = acc1 * a2, d2 = acc2 * a2, d3 = acc3 * a2;
  #pragma unroll
  for (int off = 32; off; off >>= 1) {
    s0 += __shfl_down(s0, off); s1 += __shfl_down(s1, off);
    s2 += __shfl_down(s2, off); s3 += __shfl_down(s3, off);
    d0 += __shfl_down(d0, off); d1 += __shfl_down(d1, off);
    d2 += __shfl_down(d2, off); d3 += __shfl_down(d3, off);
  }
  if (lane == 0) {
    ws[WS_ESRC + grow + 0] = s0; ws[WS_ESRC + grow + 1] = s1;
    ws[WS_ESRC + grow + 2] = s2; ws[WS_ESRC + grow + 3] = s3;
    ull* keyA = (ull*)(ws + WS_KEYA);
    keyA[grow + 0] = ((ull)mono_enc(d0) << 32) | (unsigned)(grow + 0);
    keyA[grow + 1] = ((ull)mono_enc(d1) << 32) | (unsigned)(grow + 1);
    keyA[grow + 2] = ((ull)mono_enc(d2) << 32) | (unsigned)(grow + 2);
    keyA[grow + 3] = ((ull)mono_enc(d3) << 32) | (unsigned)(grow + 3);
  }
}

// ---------------- K2a: 32 blocks, each bitonic-sorts a 256-key chunk in LDS ----------------
__global__ __launch_bounds__(256) void k2a_local(ull* __restrict__ keys) {
  __shared__ ull lk[256];
  const int t = threadIdx.x;
  const int base = blockIdx.x * 256;
  lk[t] = keys[base + t];
  __syncthreads();
  for (int k = 2; k <= 256; k <<= 1) {
    for (int j = k >> 1; j > 0; j >>= 1) {
      int p = t ^ j;
      if (p > t) {
        ull x = lk[t], y = lk[p];
        bool asc = ((t & k) == 0);
        if ((x > y) == asc) { lk[t] = y; lk[p] = x; }
      }
      __syncthreads();
    }
  }
  keys[base + t] = lk[t];
}

// ---------------- K2b: parallel merge round — runs of RUN -> runs of 2*RUN ----------------
// Keys are unique (low 32 bits = j), so pos = own_index + count(other_run < key).
template <int RUN>
__global__ __launch_bounds__(256) void k_merge(const ull* __restrict__ src,
                                               ull* __restrict__ dst) {
  const int g = blockIdx.x * 256 + threadIdx.x;
  const ull key = src[g];
  const int pairbase = g & ~(2 * RUN - 1);
  const int local = g - pairbase;
  const bool inA = local < RUN;
  const ull* other = src + pairbase + (inA ? RUN : 0);
  const int idx = inA ? local : (local - RUN);
  int lo = 0, hi = RUN;
  while (lo < hi) {
    int m = (lo + hi) >> 1;
    if (other[m] < key) lo = m + 1; else hi = m;
  }
  dst[pairbase + idx + lo] = key;
}

// ---------------- K3: block-sampled exclusive prefix sums over sorted order ----------------
// blocks 0..63: column c; block 64: scalar denominators. Thread t owns sorted
// elements [32t, 32t+32); boundary table index b == t. Tables laid out [b][c].
__global__ __launch_bounds__(256) void k3_scan(float* __restrict__ ws) {
  const ull* keys = (const ull*)(ws + WS_KEYB);
  const float* Wh = ws + WS_WH;
  const int c = blockIdx.x;
  const bool isD = (c >= F_OUT);
  __shared__ float s1[256], s2[256];
  const int t = threadIdx.x;
  const int base = t * SBLK;

  float a1 = 0.f, a2 = 0.f;
  for (int q = 0; q < SBLK; ++q) {
    ull key = keys[base + q];
    float d = mono_dec((unsigned)(key >> 32));
    float e1 = __expf(d), e2 = __expf(LRELU_ALPHA * d);
    float v = 1.0f;
    if (!isD) v = Wh[(int)(key & 0xFFFFFFFFu) * F_OUT + c];
    a1 = fmaf(e1, v, a1);
    a2 = fmaf(e2, v, a2);
  }
  s1[t] = a1; s2[t] = a2;
  __syncthreads();
  for (int off = 1; off < 256; off <<= 1) {
    float x1 = (t >= off) ? s1[t - off] : 0.f;
    float x2 = (t >= off) ? s2[t - off] : 0.f;
    __syncthreads();
    s1[t] += x1; s2[t] += x2;
    __syncthreads();
  }
  float o1 = s1[t] - a1, o2 = s2[t] - a2;   // exclusive prefix at element 32t

  if (!isD) {
    ws[WS_BP1 + t * F_OUT + c] = o1;
    ws[WS_BP2 + t * F_OUT + c] = o2;
    if (t == 255) {
      ws[WS_BP1 + NB * F_OUT + c] = s1[255];
      ws[WS_BP2 + NB * F_OUT + c] = s2[255];
    }
  } else {
    ws[WS_BD1 + t] = o1;
    ws[WS_BD2 + t] = o2;
    if (t == 255) { ws[WS_BD1 + NB] = s1[255]; ws[WS_BD2 + NB] = s2[255]; }
  }
}

// ---------------- K4: per-row binary search + table lookup + residual + ELU ----------------
// grid 2048 x 256. One wave per row, lane = output column.
__global__ __launch_bounds__(256) void k4_out(const float* __restrict__ ws,
                                              float* __restrict__ out) {
  const ull* keys = (const ull*)(ws + WS_KEYB);
  const int t = threadIdx.x;
  const int wave = t >> 6, lane = t & 63;
  const int i = blockIdx.x * 4 + wave;

  const float s = ws[WS_ESRC + i];
  // ti = first sorted index u with fl(s + d_u) > 0 (exact f32 reference predicate;
  // monotone in u since d ascends and f32 add is monotone)
  int lo = 0, hi = N_ROWS;
  while (lo < hi) {
    int m = (lo + hi) >> 1;
    float d = mono_dec((unsigned)(keys[m] >> 32));
    if (s + d > 0.0f) hi = m; else lo = m + 1;
  }
  const int ti = lo;
  const int b = ti >> 5, base = b << 5, r = ti - base;   // r in [0,32)

  // stage the boundary block's keys across lanes 0..31
  float e1l = 0.f, e2l = 0.f; int jl = 0;
  if (lane < SBLK && base + lane < N_ROWS) {
    ull key = keys[base + lane];
    float d = mono_dec((unsigned)(key >> 32));
    e1l = __expf(d); e2l = __expf(LRELU_ALPHA * d);
    jl = (int)(key & 0xFFFFFFFFu);
  }

  const float* Wh = ws + WS_WH;
  float p1 = ws[WS_BP1 + b * F_OUT + lane];
  float p2 = ws[WS_BP2 + b * F_OUT + lane];
  const float p1tot = ws[WS_BP1 + NB * F_OUT + lane];
  float d1 = ws[WS_BD1 + b], d2 = ws[WS_BD2 + b];
  const float d1tot = ws[WS_BD1 + NB];

  for (int u = 0; u < r; ++u) {       // residual terms inside boundary block
    float e1u = __shfl(e1l, u), e2u = __shfl(e2l, u);
    int ju = __shfl(jl, u);
    float w = Wh[ju * F_OUT + lane];  // coalesced 256B gather, L2-hot
    p1 = fmaf(e1u, w, p1); p2 = fmaf(e2u, w, p2);
    d1 += e1u; d2 += e2u;
  }

  const float es1 = __expf(s), es2 = __expf(LRELU_ALPHA * s);
  const float num = es1 * (p1tot - p1) + es2 * p2;
  const float den = es1 * (d1tot - d1) + es2 * d2;
  const float rr = num / den;
  out[i * F_OUT + lane] = (rr > 0.f) ? rr : (__expf(rr) - 1.f);
}

extern "C" void kernel_launch(void* const* d_in, const int* in_sizes, int n_in,
                              void* d_out, int out_size, void* d_ws, size_t ws_size,
                              hipStream_t stream) {
  const float* h = (const float*)d_in[0];
  const float* W = (const float*)d_in[1];
  const float* a = (const float*)d_in[2];
  float* ws = (float*)d_ws;
  float* out = (float*)d_out;
  ull* keyA = (ull*)(ws + WS_KEYA);
  ull* keyB = (ull*)(ws + WS_KEYB);

  hipLaunchKernelGGL(k1_wh,        dim3(N_ROWS / 16), dim3(256), 0, stream, h, W, a, ws);
  hipLaunchKernelGGL(k2a_local,    dim3(32),          dim3(256), 0, stream, keyA);
  hipLaunchKernelGGL(k_merge<256>, dim3(32),          dim3(256), 0, stream, keyA, keyB);
  hipLaunchKernelGGL(k_merge<512>, dim3(32),          dim3(256), 0, stream, keyB, keyA);
  hipLaunchKernelGGL(k_merge<1024>,dim3(32),          dim3(256), 0, stream, keyA, keyB);
  hipLaunchKernelGGL(k_merge<2048>,dim3(32),          dim3(256), 0, stream, keyB, keyA);
  hipLaunchKernelGGL(k_merge<4096>,dim3(32),          dim3(256), 0, stream, keyA, keyB);
  hipLaunchKernelGGL(k3_scan,      dim3(F_OUT + 1),   dim3(256), 0, stream, ws);
  hipLaunchKernelGGL(k4_out,       dim3(N_ROWS / 4),  dim3(256), 0, stream, ws, out);
}